// Round 2
// baseline (2152.132 us; speedup 1.0000x reference)
//
#include <hip/hip_runtime.h>

#define NU 100000
#define NI 100000
#define NE 1000000
#define C  128
#define CC (C*C)

// ---------------- CSR build ----------------
__global__ void count_edges(const int* __restrict__ ei, int* __restrict__ cnt) {
  int e = blockIdx.x * blockDim.x + threadIdx.x;
  int stride = gridDim.x * blockDim.x;
  for (; e < NE; e += stride)
    atomicAdd(&cnt[ei[NE + e]], 1);
}

// single-block exclusive scan of cnt[0..N-1] -> rowptr[0..N], zeroing cnt as it goes
__global__ void scan_excl(const int* __restrict__ cnt, int* __restrict__ rowptr,
                          int* __restrict__ cnt_zero, int N) {
  __shared__ int wls[4];
  int tid = threadIdx.x;
  int lane = tid & 63, w = tid >> 6;
  int running = 0;
  for (int base = 0; base < N; base += 2048) {
    int idx0 = base + tid * 8;
    int c[8], pre[8];
    int tsum = 0;
#pragma unroll
    for (int i = 0; i < 8; ++i) {
      c[i] = (idx0 + i < N) ? cnt[idx0 + i] : 0;
      pre[i] = tsum; tsum += c[i];
    }
    int inc = tsum;
#pragma unroll
    for (int d = 1; d < 64; d <<= 1) {
      int v = __shfl_up(inc, d, 64);
      if (lane >= d) inc += v;
    }
    if (lane == 63) wls[w] = inc;
    __syncthreads();
    int wbase = 0;
#pragma unroll
    for (int ww = 0; ww < 4; ++ww) { if (ww < w) wbase += wls[ww]; }
    int ctot = wls[0] + wls[1] + wls[2] + wls[3];
    int toff = running + wbase + (inc - tsum);
#pragma unroll
    for (int i = 0; i < 8; ++i)
      if (idx0 + i < N) { rowptr[idx0 + i] = toff + pre[i]; cnt_zero[idx0 + i] = 0; }
    running += ctot;
    __syncthreads();
  }
  if (tid == 0) rowptr[N] = running;
}

__global__ void fill_edges(const int* __restrict__ ei, const int* __restrict__ rowptr,
                           int* __restrict__ cursor, int* __restrict__ elist) {
  int e = blockIdx.x * blockDim.x + threadIdx.x;
  int stride = gridDim.x * blockDim.x;
  for (; e < NE; e += stride) {
    int s = ei[e], d = ei[NE + e];
    int p = rowptr[d] + atomicAdd(&cursor[d], 1);
    elist[p] = s;
  }
}

// ---------------- mean aggregation: one wave per dst ----------------
__global__ void agg_mean(const float* __restrict__ x, const int* __restrict__ rowptr,
                         const int* __restrict__ elist, float* __restrict__ mean, int Ndst) {
  int gw = (blockIdx.x * blockDim.x + threadIdx.x) >> 6;
  int lane = threadIdx.x & 63;
  if (gw >= Ndst) return;
  int beg = rowptr[gw], end = rowptr[gw + 1];
  float ax = 0.f, ay = 0.f;
  for (int j = beg; j < end; ++j) {
    int s = elist[j];
    float2 v = *(const float2*)&x[(size_t)s * C + lane * 2];
    ax += v.x; ay += v.y;
  }
  int n = end - beg;
  float inv = 1.0f / (float)(n > 0 ? n : 1);
  float2 r; r.x = ax * inv; r.y = ay * inv;
  *(float2*)&mean[(size_t)gw * C + lane * 2] = r;
}

// ---------------- Wr1 + Wr2 prep (per layer) ----------------
__global__ void wprep(const float* __restrict__ Wr, float* __restrict__ wsum) {
  int i = blockIdx.x * blockDim.x + threadIdx.x;
  if (i >= 2 * CC) return;
  int l = i >> 14;          // CC == 16384
  int r = i & (CC - 1);
  wsum[i] = Wr[(size_t)(l * 3 + 1) * CC + r] + Wr[(size_t)(l * 3 + 2) * CC + r];
}

// ---------------- fused multi-segment GEMM + bias + LayerNorm + ReLU ----------------
// out[M x 128] = sum_s A_s[M x 128] @ B_s[128 x 128]  + bias0 (+bias1), then LN(row)*lnw+lnb, ReLU
#define BM 128
#define BK 16
#define LDT 132

__global__ void gemm_ln_relu(const float* __restrict__ A0, const float* __restrict__ A1,
                             const float* __restrict__ A2,
                             const float* __restrict__ B0, const float* __restrict__ B1,
                             const float* __restrict__ B2,
                             const float* __restrict__ bias0, const float* __restrict__ bias1,
                             const float* __restrict__ lnw, const float* __restrict__ lnb,
                             float* __restrict__ out, int M, int nseg) {
  __shared__ float As[BK][LDT];   // transposed: As[k][row]
  __shared__ float Bs[BK][LDT];   // Bs[k][n]
  int tid = threadIdx.x;
  int tn = tid & 15, tm = tid >> 4;       // 16 x 16 thread grid, 8x8 micro-tile
  int row0 = blockIdx.x * BM;
  float acc[8][8];
#pragma unroll
  for (int i = 0; i < 8; ++i)
#pragma unroll
    for (int j = 0; j < 8; ++j) acc[i][j] = 0.f;

  const float* Aseg[3] = {A0, A1, A2};
  const float* Bseg[3] = {B0, B1, B2};

  int lac4 = (tid & 3) * 4;  // A tile col
  int lar  = tid >> 2;       // A tile row (0..63), +64 on second pass
  int lbn  = (tid & 31) * 4; // B tile col
  int lbk  = tid >> 5;       // B tile row (0..7), +8 on second pass

  for (int s = 0; s < nseg; ++s) {
    const float* A = Aseg[s];
    const float* B = Bseg[s];
    for (int k0 = 0; k0 < C; k0 += BK) {
#pragma unroll
      for (int p = 0; p < 2; ++p) {
        int r = lar + p * 64;
        int gr = row0 + r;
        float4 v = make_float4(0.f, 0.f, 0.f, 0.f);
        if (gr < M) v = *(const float4*)&A[(size_t)gr * C + k0 + lac4];
        As[lac4 + 0][r] = v.x;
        As[lac4 + 1][r] = v.y;
        As[lac4 + 2][r] = v.z;
        As[lac4 + 3][r] = v.w;
      }
#pragma unroll
      for (int p = 0; p < 2; ++p) {
        int k = lbk + p * 8;
        *(float4*)&Bs[k][lbn] = *(const float4*)&B[(size_t)(k0 + k) * C + lbn];
      }
      __syncthreads();
#pragma unroll
      for (int k = 0; k < BK; ++k) {
        float a[8], b[8];
        *(float4*)&a[0] = *(const float4*)&As[k][tm * 8];
        *(float4*)&a[4] = *(const float4*)&As[k][tm * 8 + 4];
        *(float4*)&b[0] = *(const float4*)&Bs[k][tn * 8];
        *(float4*)&b[4] = *(const float4*)&Bs[k][tn * 8 + 4];
#pragma unroll
        for (int i = 0; i < 8; ++i)
#pragma unroll
          for (int j = 0; j < 8; ++j)
            acc[i][j] = fmaf(a[i], b[j], acc[i][j]);
      }
      __syncthreads();
    }
  }

  // bias
  float bj[8], wv[8], bv[8];
#pragma unroll
  for (int j = 0; j < 8; ++j) {
    int col = tn * 8 + j;
    bj[j] = bias0[col] + (bias1 ? bias1[col] : 0.f);
    wv[j] = lnw[col];
    bv[j] = lnb[col];
  }
#pragma unroll
  for (int i = 0; i < 8; ++i)
#pragma unroll
    for (int j = 0; j < 8; ++j) acc[i][j] += bj[j];

  // LayerNorm across the 128 cols of each row (held by 16 lanes: tn = lane&15), + ReLU
#pragma unroll
  for (int i = 0; i < 8; ++i) {
    float s = 0.f;
#pragma unroll
    for (int j = 0; j < 8; ++j) s += acc[i][j];
    s += __shfl_xor(s, 1, 64);
    s += __shfl_xor(s, 2, 64);
    s += __shfl_xor(s, 4, 64);
    s += __shfl_xor(s, 8, 64);
    float mu = s * (1.0f / C);
    float v = 0.f;
#pragma unroll
    for (int j = 0; j < 8; ++j) { float d = acc[i][j] - mu; v = fmaf(d, d, v); }
    v += __shfl_xor(v, 1, 64);
    v += __shfl_xor(v, 2, 64);
    v += __shfl_xor(v, 4, 64);
    v += __shfl_xor(v, 8, 64);
    float rs = rsqrtf(v * (1.0f / C) + 1e-5f);
    int gr = row0 + tm * 8 + i;
    if (gr < M) {
      float o[8];
#pragma unroll
      for (int j = 0; j < 8; ++j) {
        float y = (acc[i][j] - mu) * rs * wv[j] + bv[j];
        o[j] = y > 0.f ? y : 0.f;
      }
      *(float4*)&out[(size_t)gr * C + tn * 8]     = *(float4*)&o[0];
      *(float4*)&out[(size_t)gr * C + tn * 8 + 4] = *(float4*)&o[4];
    }
  }
}

extern "C" void kernel_launch(void* const* d_in, const int* in_sizes, int n_in,
                              void* d_out, int out_size, void* d_ws, size_t ws_size,
                              hipStream_t stream) {
  (void)in_sizes; (void)n_in; (void)out_size;
  const float* xu0 = (const float*)d_in[0];
  const float* xi0 = (const float*)d_in[1];
  const int* eui = (const int*)d_in[2];
  const int* eiu = (const int*)d_in[3];
  const int* euu = (const int*)d_in[4];
  const float* Wl = (const float*)d_in[5];
  const float* bl = (const float*)d_in[6];
  const float* Wr = (const float*)d_in[7];
  const float* lnw = (const float*)d_in[8];
  const float* lnb = (const float*)d_in[9];
  float* out_u = (float*)d_out;
  float* out_i = (float*)d_out + (size_t)NU * C;

  char* w = (char*)d_ws;
  size_t used = 0;
  auto alloc = [&](size_t bytes) {
    char* p = w; size_t pad = (bytes + 255) & ~(size_t)255;
    w += pad; used += pad; return p;
  };
  float* mean_ui = (float*)alloc((size_t)NI * C * 4);
  float* mean_iu = (float*)alloc((size_t)NU * C * 4);
  float* mean_uu = (float*)alloc((size_t)NU * C * 4);
  int* rp_ui = (int*)alloc((NI + 1) * 4);
  int* rp_iu = (int*)alloc((NU + 1) * 4);
  int* rp_uu = (int*)alloc((NU + 1) * 4);
  int* el_ui = (int*)alloc((size_t)NE * 4);
  int* el_iu = (int*)alloc((size_t)NE * 4);
  int* el_uu = (int*)alloc((size_t)NE * 4);
  int* cur = (int*)alloc((size_t)3 * NU * 4);
  int* cur_ui = cur; int* cur_iu = cur + NU; int* cur_uu = cur + 2 * NU;
  float* wsum = (float*)alloc((size_t)2 * CC * 4);

  // Guard: if workspace is too small, do NOT write OOB (would crash the
  // container). Clean absmax failure is the diagnostic instead.
  if (used > ws_size) return;

  // ---- CSR build (edge structure is launch-invariant; build once per launch) ----
  hipMemsetAsync(cur, 0, (size_t)3 * NU * 4, stream);
  count_edges<<<1024, 256, 0, stream>>>(eui, cur_ui);
  count_edges<<<1024, 256, 0, stream>>>(eiu, cur_iu);
  count_edges<<<1024, 256, 0, stream>>>(euu, cur_uu);
  scan_excl<<<1, 256, 0, stream>>>(cur_ui, rp_ui, cur_ui, NI);
  scan_excl<<<1, 256, 0, stream>>>(cur_iu, rp_iu, cur_iu, NU);
  scan_excl<<<1, 256, 0, stream>>>(cur_uu, rp_uu, cur_uu, NU);
  fill_edges<<<1024, 256, 0, stream>>>(eui, rp_ui, cur_ui, el_ui);
  fill_edges<<<1024, 256, 0, stream>>>(eiu, rp_iu, cur_iu, el_iu);
  fill_edges<<<1024, 256, 0, stream>>>(euu, rp_uu, cur_uu, el_uu);
  wprep<<<(2 * CC + 255) / 256, 256, 0, stream>>>(Wr, wsum);

  for (int l = 0; l < 2; ++l) {
    const float* xu = l ? (const float*)out_u : xu0;
    const float* xi = l ? (const float*)out_i : xi0;
    int aggBlocksI = (NI + 3) / 4;   // 4 waves (dsts) per 256-thread block
    int aggBlocksU = (NU + 3) / 4;
    agg_mean<<<aggBlocksI, 256, 0, stream>>>(xu, rp_ui, el_ui, mean_ui, NI);
    agg_mean<<<aggBlocksU, 256, 0, stream>>>(xi, rp_iu, el_iu, mean_iu, NU);
    agg_mean<<<aggBlocksU, 256, 0, stream>>>(xu, rp_uu, el_uu, mean_uu, NU);
    int gbU = (NU + BM - 1) / BM;
    int gbI = (NI + BM - 1) / BM;
    // user: [mean_iu | mean_uu | xu] @ [Wl1; Wl2; Wr1+Wr2] + b1 + b2, LN(user), ReLU
    gemm_ln_relu<<<gbU, 256, 0, stream>>>(mean_iu, mean_uu, xu,
        Wl + (size_t)(l * 3 + 1) * CC, Wl + (size_t)(l * 3 + 2) * CC, wsum + (size_t)l * CC,
        bl + (l * 3 + 1) * C, bl + (l * 3 + 2) * C,
        lnw + (l * 2 + 0) * C, lnb + (l * 2 + 0) * C, out_u, NU, 3);
    // item: [mean_ui | xi] @ [Wl0; Wr0] + b0, LN(item), ReLU
    gemm_ln_relu<<<gbI, 256, 0, stream>>>(mean_ui, xi, nullptr,
        Wl + (size_t)(l * 3 + 0) * CC, Wr + (size_t)(l * 3 + 0) * CC, nullptr,
        bl + (l * 3 + 0) * C, nullptr,
        lnw + (l * 2 + 1) * C, lnb + (l * 2 + 1) * C, out_i, NI, 2);
  }
}

// Round 3
// 1323.474 us; speedup vs baseline: 1.6261x; 1.6261x over previous
//
#include <hip/hip_runtime.h>

#define NU 100000
#define NI 100000
#define NE 1000000
#define C  128
#define CC (C*C)
#define BM 128

typedef unsigned int uint;
typedef unsigned short ushort;
using bf16x8 = __attribute__((ext_vector_type(8))) short;
using f32x4  = __attribute__((ext_vector_type(4))) float;

__device__ __forceinline__ ushort f2bf(float f) {
  uint u = __builtin_bit_cast(uint, f);
  u = (u + 0x7fffu + ((u >> 16) & 1u)) >> 16;   // RNE
  return (ushort)u;
}
__device__ __forceinline__ float bf2f(ushort h) {
  return __builtin_bit_cast(float, (uint)h << 16);
}

// ---------------- f32 -> bf16 table conversion (two tables per call) ----------------
__global__ void conv2bf(const float* __restrict__ a, ushort* __restrict__ ab,
                        const float* __restrict__ b, ushort* __restrict__ bb, int n4) {
  int i = blockIdx.x * blockDim.x + threadIdx.x;
  int st = gridDim.x * blockDim.x;
  for (; i < n4; i += st) {
    float4 va = ((const float4*)a)[i];
    ushort4 ra; ra.x = f2bf(va.x); ra.y = f2bf(va.y); ra.z = f2bf(va.z); ra.w = f2bf(va.w);
    ((ushort4*)ab)[i] = ra;
    float4 vb = ((const float4*)b)[i];
    ushort4 rb; rb.x = f2bf(vb.x); rb.y = f2bf(vb.y); rb.z = f2bf(vb.z); rb.w = f2bf(vb.w);
    ((ushort4*)bb)[i] = rb;
  }
}

// ---------------- CSR build ----------------
__global__ void count_all(const int* __restrict__ eui, const int* __restrict__ eiu,
                          const int* __restrict__ euu,
                          int* __restrict__ cui, int* __restrict__ ciu, int* __restrict__ cuu) {
  int gid = blockIdx.x * blockDim.x + threadIdx.x;
  int st = gridDim.x * blockDim.x;
  for (int e = gid; e < NE; e += st) atomicAdd(&cui[eui[NE + e]], 1);
  for (int e = gid; e < NE; e += st) atomicAdd(&ciu[eiu[NE + e]], 1);
  for (int e = gid; e < NE; e += st) atomicAdd(&cuu[euu[NE + e]], 1);
}

// 3 blocks; block b scans its array (N=100000), zeroing cnt for cursor reuse
__global__ void scan3(int* c0, int* r0, int* c1, int* r1, int* c2, int* r2) {
  const int N = 100000;
  int* cnt    = blockIdx.x == 0 ? c0 : (blockIdx.x == 1 ? c1 : c2);
  int* rowptr = blockIdx.x == 0 ? r0 : (blockIdx.x == 1 ? r1 : r2);
  __shared__ int wls[4];
  int tid = threadIdx.x;
  int lane = tid & 63, w = tid >> 6;
  int running = 0;
  for (int base = 0; base < N; base += 2048) {
    int idx0 = base + tid * 8;
    int c[8], pre[8];
    int tsum = 0;
#pragma unroll
    for (int i = 0; i < 8; ++i) {
      c[i] = (idx0 + i < N) ? cnt[idx0 + i] : 0;
      pre[i] = tsum; tsum += c[i];
    }
    int inc = tsum;
#pragma unroll
    for (int d = 1; d < 64; d <<= 1) {
      int v = __shfl_up(inc, d, 64);
      if (lane >= d) inc += v;
    }
    if (lane == 63) wls[w] = inc;
    __syncthreads();
    int wbase = 0;
#pragma unroll
    for (int ww = 0; ww < 4; ++ww) { if (ww < w) wbase += wls[ww]; }
    int ctot = wls[0] + wls[1] + wls[2] + wls[3];
    int toff = running + wbase + (inc - tsum);
#pragma unroll
    for (int i = 0; i < 8; ++i)
      if (idx0 + i < N) { rowptr[idx0 + i] = toff + pre[i]; cnt[idx0 + i] = 0; }
    running += ctot;
    __syncthreads();
  }
  if (tid == 0) rowptr[N] = running;
}

__global__ void fill_all(const int* __restrict__ eui, const int* __restrict__ eiu,
                         const int* __restrict__ euu,
                         const int* __restrict__ rui, const int* __restrict__ riu,
                         const int* __restrict__ ruu,
                         int* __restrict__ cui, int* __restrict__ ciu, int* __restrict__ cuu,
                         int* __restrict__ lui, int* __restrict__ liu, int* __restrict__ luu) {
  int gid = blockIdx.x * blockDim.x + threadIdx.x;
  int st = gridDim.x * blockDim.x;
  for (int e = gid; e < NE; e += st) {
    int d = eui[NE + e];
    lui[rui[d] + atomicAdd(&cui[d], 1)] = eui[e];
  }
  for (int e = gid; e < NE; e += st) {
    int d = eiu[NE + e];
    liu[riu[d] + atomicAdd(&ciu[d], 1)] = eiu[e];
  }
  for (int e = gid; e < NE; e += st) {
    int d = euu[NE + e];
    luu[ruu[d] + atomicAdd(&cuu[d], 1)] = euu[e];
  }
}

// ---------------- weight prep: bf16 B^T, packed per layer ----------------
// BtU: [2][128 cols][384 kt], BtI: [2][128 cols][256 kt]
__global__ void prep_w(const float* __restrict__ Wl, const float* __restrict__ Wr,
                       ushort* __restrict__ BtU, ushort* __restrict__ BtI) {
  int i = blockIdx.x * blockDim.x + threadIdx.x;
  const int nU = 2 * C * 384;
  const int nI = 2 * C * 256;
  if (i < nU) {
    int l = i / (C * 384); int rem = i - l * (C * 384);
    int n = rem / 384; int kt = rem - n * 384;
    float v;
    if (kt < 128)       v = Wl[((size_t)(l * 3 + 1) * C + kt) * C + n];
    else if (kt < 256)  v = Wl[((size_t)(l * 3 + 2) * C + (kt - 128)) * C + n];
    else                v = Wr[((size_t)(l * 3 + 1) * C + (kt - 256)) * C + n]
                          + Wr[((size_t)(l * 3 + 2) * C + (kt - 256)) * C + n];
    BtU[i] = f2bf(v);
  } else if (i < nU + nI) {
    int j = i - nU;
    int l = j / (C * 256); int rem = j - l * (C * 256);
    int n = rem / 256; int kt = rem - n * 256;
    float v = (kt < 128) ? Wl[((size_t)(l * 3 + 0) * C + kt) * C + n]
                         : Wr[((size_t)(l * 3 + 0) * C + (kt - 128)) * C + n];
    BtI[j] = f2bf(v);
  }
}

// ---------------- merged mean aggregation (bf16 gather): one wave per dst ----------------
__global__ void agg_all(const ushort* __restrict__ xub, const ushort* __restrict__ xib,
                        const int* __restrict__ rpui, const int* __restrict__ elui, ushort* __restrict__ mui,
                        const int* __restrict__ rpiu, const int* __restrict__ eliu, ushort* __restrict__ miu,
                        const int* __restrict__ rpuu, const int* __restrict__ eluu, ushort* __restrict__ muu) {
  int gw = (blockIdx.x * blockDim.x + threadIdx.x) >> 6;
  int lane = threadIdx.x & 63;
  const ushort* x; const int* rp; const int* el; ushort* m; int d;
  if (gw < NI)            { x = xub; rp = rpui; el = elui; m = mui; d = gw; }
  else if (gw < NI + NU)  { x = xib; rp = rpiu; el = eliu; m = miu; d = gw - NI; }
  else if (gw < NI + 2*NU){ x = xub; rp = rpuu; el = eluu; m = muu; d = gw - NI - NU; }
  else return;
  int beg = rp[d], end = rp[d + 1];
  float ax = 0.f, ay = 0.f;
  for (int j = beg; j < end; ++j) {
    int s = el[j];
    uint v = *(const uint*)&x[(size_t)s * C + lane * 2];
    ax += bf2f((ushort)(v & 0xffffu));
    ay += bf2f((ushort)(v >> 16));
  }
  int n = end - beg;
  float inv = 1.0f / (float)(n > 0 ? n : 1);
  uint r = (uint)f2bf(ax * inv) | ((uint)f2bf(ay * inv) << 16);
  *(uint*)&m[(size_t)d * C + lane * 2] = r;
}

// ---------------- fused MFMA GEMM + bias + LayerNorm + ReLU (user & item in one grid) --------
struct GemmParams {
  const ushort *Au0, *Au1, *Au2, *BtU;
  const float  *bu0, *bu1, *lnwU, *lnbU;
  float* outU;
  const ushort *Ai0, *Ai1, *BtI;
  const float  *bi0, *lnwI, *lnbI;
  float* outI;
  int gbU;
};

__global__ __launch_bounds__(256) void gemm_mfma_ln(GemmParams p) {
  __shared__ __align__(16) char smem[16384];
  char* Al = smem;            // A tile: 128 rows x 32 k (bf16), swizzled, 64B/row
  char* Bl = smem + 8192;     // B tile: 128 cols x 32 k (bf16), swizzled
  int tid = threadIdx.x;
  bool isU = (int)blockIdx.x < p.gbU;
  const ushort* Aseg[3]; const ushort* Bt; int KT, M;
  const float *bias0, *bias1, *lnw, *lnb; float* outp;
  if (isU) {
    Aseg[0] = p.Au0; Aseg[1] = p.Au1; Aseg[2] = p.Au2; Bt = p.BtU; KT = 384; M = NU;
    bias0 = p.bu0; bias1 = p.bu1; lnw = p.lnwU; lnb = p.lnbU; outp = p.outU;
  } else {
    Aseg[0] = p.Ai0; Aseg[1] = p.Ai1; Aseg[2] = p.Ai1; Bt = p.BtI; KT = 256; M = NI;
    bias0 = p.bi0; bias1 = nullptr; lnw = p.lnwI; lnb = p.lnbI; outp = p.outI;
  }
  int row0 = (isU ? (int)blockIdx.x : (int)blockIdx.x - p.gbU) * BM;

  int w = tid >> 6, lane = tid & 63;
  int l15 = lane & 15, l4 = lane >> 4;
  int srow = tid >> 1, shalf = tid & 1;           // staging: 2 threads per row/col
  int s0 = shalf * 2;
  int sw = ((srow >> 1) & 3) << 4;                // swizzle bits for staging row

  // fragment ds_read byte offsets (swizzled)
  int abyte[2], bbyte[8];
#pragma unroll
  for (int r = 0; r < 2; ++r) {
    int row = w * 32 + r * 16 + l15;
    abyte[r] = row * 64 + (((l4 << 4)) ^ (((row >> 1) & 3) << 4));
  }
#pragma unroll
  for (int c = 0; c < 8; ++c) {
    int col = c * 16 + l15;
    bbyte[c] = col * 64 + (((l4 << 4)) ^ (((col >> 1) & 3) << 4));
  }

  f32x4 acc[2][8];
#pragma unroll
  for (int r = 0; r < 2; ++r)
#pragma unroll
    for (int c = 0; c < 8; ++c) acc[r][c] = (f32x4){0.f, 0.f, 0.f, 0.f};

  for (int kt0 = 0; kt0 < KT; kt0 += 32) {
    // stage A (rows of [mean… | x]) — 32 ushorts per row, 2 threads x 32B
    int seg = kt0 >> 7, kin = kt0 & 127;
    const ushort* Ag = Aseg[seg];
    int gr = row0 + srow;
    bf16x8 va0 = {}, va1 = {};
    if (gr < M) {
      const ushort* ga = Ag + (size_t)gr * C + kin + shalf * 16;
      va0 = *(const bf16x8*)(ga);
      va1 = *(const bf16x8*)(ga + 8);
    }
    *(bf16x8*)(Al + srow * 64 + ((s0 << 4) ^ sw))       = va0;
    *(bf16x8*)(Al + srow * 64 + (((s0 + 1) << 4) ^ sw)) = va1;
    // stage B^T (col-major-packed weights)
    const ushort* gb = Bt + (size_t)srow * KT + kt0 + shalf * 16;
    bf16x8 vb0 = *(const bf16x8*)(gb);
    bf16x8 vb1 = *(const bf16x8*)(gb + 8);
    *(bf16x8*)(Bl + srow * 64 + ((s0 << 4) ^ sw))       = vb0;
    *(bf16x8*)(Bl + srow * 64 + (((s0 + 1) << 4) ^ sw)) = vb1;
    __syncthreads();

    bf16x8 af[2], bfr[8];
#pragma unroll
    for (int r = 0; r < 2; ++r) af[r] = *(const bf16x8*)(Al + abyte[r]);
#pragma unroll
    for (int c = 0; c < 8; ++c) bfr[c] = *(const bf16x8*)(Bl + bbyte[c]);
#pragma unroll
    for (int r = 0; r < 2; ++r)
#pragma unroll
      for (int c = 0; c < 8; ++c)
        acc[r][c] = __builtin_amdgcn_mfma_f32_16x16x32_bf16(af[r], bfr[c], acc[r][c], 0, 0, 0);
    __syncthreads();
  }

  // epilogue: bias + LayerNorm(row of 128) + ReLU
  float bj[8], wv[8], bvv[8];
#pragma unroll
  for (int c = 0; c < 8; ++c) {
    int col = c * 16 + l15;
    bj[c]  = bias0[col] + (bias1 ? bias1[col] : 0.f);
    wv[c]  = lnw[col];
    bvv[c] = lnb[col];
  }
#pragma unroll
  for (int r = 0; r < 2; ++r) {
#pragma unroll
    for (int i = 0; i < 4; ++i) {
      float v[8];
#pragma unroll
      for (int c = 0; c < 8; ++c) v[c] = acc[r][c][i] + bj[c];
      float s = 0.f;
#pragma unroll
      for (int c = 0; c < 8; ++c) s += v[c];
      s += __shfl_xor(s, 1, 64);
      s += __shfl_xor(s, 2, 64);
      s += __shfl_xor(s, 4, 64);
      s += __shfl_xor(s, 8, 64);
      float mu = s * (1.0f / C);
      float var = 0.f;
#pragma unroll
      for (int c = 0; c < 8; ++c) { float d = v[c] - mu; var = fmaf(d, d, var); }
      var += __shfl_xor(var, 1, 64);
      var += __shfl_xor(var, 2, 64);
      var += __shfl_xor(var, 4, 64);
      var += __shfl_xor(var, 8, 64);
      float rs = rsqrtf(var * (1.0f / C) + 1e-5f);
      int grow = row0 + w * 32 + r * 16 + l4 * 4 + i;
      if (grow < M) {
#pragma unroll
        for (int c = 0; c < 8; ++c) {
          float y = (v[c] - mu) * rs * wv[c] + bvv[c];
          outp[(size_t)grow * C + c * 16 + l15] = y > 0.f ? y : 0.f;
        }
      }
    }
  }
}

extern "C" void kernel_launch(void* const* d_in, const int* in_sizes, int n_in,
                              void* d_out, int out_size, void* d_ws, size_t ws_size,
                              hipStream_t stream) {
  (void)in_sizes; (void)n_in; (void)out_size;
  const float* xu0 = (const float*)d_in[0];
  const float* xi0 = (const float*)d_in[1];
  const int* eui = (const int*)d_in[2];
  const int* eiu = (const int*)d_in[3];
  const int* euu = (const int*)d_in[4];
  const float* Wl = (const float*)d_in[5];
  const float* bl = (const float*)d_in[6];
  const float* Wr = (const float*)d_in[7];
  const float* lnw = (const float*)d_in[8];
  const float* lnb = (const float*)d_in[9];
  float* out_u = (float*)d_out;
  float* out_i = (float*)d_out + (size_t)NU * C;

  char* w = (char*)d_ws;
  size_t used = 0;
  auto alloc = [&](size_t bytes) {
    char* p = w; size_t pad = (bytes + 255) & ~(size_t)255;
    w += pad; used += pad; return p;
  };
  ushort* x0ub = (ushort*)alloc((size_t)NU * C * 2);
  ushort* x0ib = (ushort*)alloc((size_t)NI * C * 2);
  ushort* x1ub = (ushort*)alloc((size_t)NU * C * 2);
  ushort* x1ib = (ushort*)alloc((size_t)NI * C * 2);
  ushort* mui  = (ushort*)alloc((size_t)NI * C * 2);
  ushort* miu  = (ushort*)alloc((size_t)NU * C * 2);
  ushort* muu  = (ushort*)alloc((size_t)NU * C * 2);
  int* rp_ui = (int*)alloc((NI + 1) * 4);
  int* rp_iu = (int*)alloc((NU + 1) * 4);
  int* rp_uu = (int*)alloc((NU + 1) * 4);
  int* el_ui = (int*)alloc((size_t)NE * 4);
  int* el_iu = (int*)alloc((size_t)NE * 4);
  int* el_uu = (int*)alloc((size_t)NE * 4);
  int* cur = (int*)alloc((size_t)3 * NU * 4);
  int* cur_ui = cur; int* cur_iu = cur + NU; int* cur_uu = cur + 2 * NU;
  ushort* BtU = (ushort*)alloc((size_t)2 * C * 384 * 2);
  ushort* BtI = (ushort*)alloc((size_t)2 * C * 256 * 2);

  if (used > ws_size) return;   // clean failure instead of OOB crash

  hipMemsetAsync(cur, 0, (size_t)3 * NU * 4, stream);
  conv2bf<<<2048, 256, 0, stream>>>(xu0, x0ub, xi0, x0ib, NU * C / 4);
  count_all<<<2048, 256, 0, stream>>>(eui, eiu, euu, cur_ui, cur_iu, cur_uu);
  scan3<<<3, 256, 0, stream>>>(cur_ui, rp_ui, cur_iu, rp_iu, cur_uu, rp_uu);
  fill_all<<<2048, 256, 0, stream>>>(eui, eiu, euu, rp_ui, rp_iu, rp_uu,
                                     cur_ui, cur_iu, cur_uu, el_ui, el_iu, el_uu);
  prep_w<<<(2 * C * 384 + 2 * C * 256 + 255) / 256, 256, 0, stream>>>(Wl, Wr, BtU, BtI);

  int gbU = (NU + BM - 1) / BM;   // 782
  int gbI = (NI + BM - 1) / BM;   // 782
  int aggBlocks = (NI + 2 * NU) / 4;  // one wave per dst, 4 waves/block

  for (int l = 0; l < 2; ++l) {
    const ushort* xub = l ? x1ub : x0ub;
    const ushort* xib = l ? x1ib : x0ib;
    agg_all<<<aggBlocks, 256, 0, stream>>>(xub, xib,
        rp_ui, el_ui, mui, rp_iu, el_iu, miu, rp_uu, el_uu, muu);
    GemmParams p;
    p.Au0 = miu; p.Au1 = muu; p.Au2 = xub; p.BtU = BtU + (size_t)l * C * 384;
    p.bu0 = bl + (l * 3 + 1) * C; p.bu1 = bl + (l * 3 + 2) * C;
    p.lnwU = lnw + (l * 2 + 0) * C; p.lnbU = lnb + (l * 2 + 0) * C; p.outU = out_u;
    p.Ai0 = mui; p.Ai1 = xib; p.BtI = BtI + (size_t)l * C * 256;
    p.bi0 = bl + (l * 3 + 0) * C;
    p.lnwI = lnw + (l * 2 + 1) * C; p.lnbI = lnb + (l * 2 + 1) * C; p.outI = out_i;
    p.gbU = gbU;
    gemm_mfma_ln<<<gbU + gbI, 256, 0, stream>>>(p);
    if (l == 0)
      conv2bf<<<2048, 256, 0, stream>>>(out_u, x1ub, out_i, x1ib, NU * C / 4);
  }
}

// Round 4
// 978.479 us; speedup vs baseline: 2.1995x; 1.3526x over previous
//
#include <hip/hip_runtime.h>

#define NU 100000
#define NI 100000
#define NE 1000000
#define C  128
#define CC (C*C)
#define BM 128

typedef unsigned int uint;
typedef unsigned short ushort;
using bf16x8 = __attribute__((ext_vector_type(8))) short;
using f32x4  = __attribute__((ext_vector_type(4))) float;

__device__ __forceinline__ ushort f2bf(float f) {
  uint u = __builtin_bit_cast(uint, f);
  u = (u + 0x7fffu + ((u >> 16) & 1u)) >> 16;   // RNE
  return (ushort)u;
}
__device__ __forceinline__ float bf2f(ushort h) {
  return __builtin_bit_cast(float, (uint)h << 16);
}

// ---------------- f32 -> bf16 table conversion (two tables per call) ----------------
__global__ void conv2bf(const float* __restrict__ a, ushort* __restrict__ ab,
                        const float* __restrict__ b, ushort* __restrict__ bb, int n4) {
  int i = blockIdx.x * blockDim.x + threadIdx.x;
  int st = gridDim.x * blockDim.x;
  for (; i < n4; i += st) {
    float4 va = ((const float4*)a)[i];
    ushort4 ra; ra.x = f2bf(va.x); ra.y = f2bf(va.y); ra.z = f2bf(va.z); ra.w = f2bf(va.w);
    ((ushort4*)ab)[i] = ra;
    float4 vb = ((const float4*)b)[i];
    ushort4 rb; rb.x = f2bf(vb.x); rb.y = f2bf(vb.y); rb.z = f2bf(vb.z); rb.w = f2bf(vb.w);
    ((ushort4*)bb)[i] = rb;
  }
}

// ---------------- CSR build ----------------
__global__ void count_all(const int* __restrict__ eui, const int* __restrict__ eiu,
                          const int* __restrict__ euu,
                          int* __restrict__ cui, int* __restrict__ ciu, int* __restrict__ cuu) {
  int gid = blockIdx.x * blockDim.x + threadIdx.x;
  int st = gridDim.x * blockDim.x;
  for (int e = gid; e < NE; e += st) atomicAdd(&cui[eui[NE + e]], 1);
  for (int e = gid; e < NE; e += st) atomicAdd(&ciu[eiu[NE + e]], 1);
  for (int e = gid; e < NE; e += st) atomicAdd(&cuu[euu[NE + e]], 1);
}

// 3 blocks; block b scans its array (N=100000), zeroing cnt for cursor reuse
__global__ void scan3(int* c0, int* r0, int* c1, int* r1, int* c2, int* r2) {
  const int N = 100000;
  int* cnt    = blockIdx.x == 0 ? c0 : (blockIdx.x == 1 ? c1 : c2);
  int* rowptr = blockIdx.x == 0 ? r0 : (blockIdx.x == 1 ? r1 : r2);
  __shared__ int wls[4];
  int tid = threadIdx.x;
  int lane = tid & 63, w = tid >> 6;
  int running = 0;
  for (int base = 0; base < N; base += 2048) {
    int idx0 = base + tid * 8;
    int c[8], pre[8];
    int tsum = 0;
#pragma unroll
    for (int i = 0; i < 8; ++i) {
      c[i] = (idx0 + i < N) ? cnt[idx0 + i] : 0;
      pre[i] = tsum; tsum += c[i];
    }
    int inc = tsum;
#pragma unroll
    for (int d = 1; d < 64; d <<= 1) {
      int v = __shfl_up(inc, d, 64);
      if (lane >= d) inc += v;
    }
    if (lane == 63) wls[w] = inc;
    __syncthreads();
    int wbase = 0;
#pragma unroll
    for (int ww = 0; ww < 4; ++ww) { if (ww < w) wbase += wls[ww]; }
    int ctot = wls[0] + wls[1] + wls[2] + wls[3];
    int toff = running + wbase + (inc - tsum);
#pragma unroll
    for (int i = 0; i < 8; ++i)
      if (idx0 + i < N) { rowptr[idx0 + i] = toff + pre[i]; cnt[idx0 + i] = 0; }
    running += ctot;
    __syncthreads();
  }
  if (tid == 0) rowptr[N] = running;
}

__global__ void fill_all(const int* __restrict__ eui, const int* __restrict__ eiu,
                         const int* __restrict__ euu,
                         const int* __restrict__ rui, const int* __restrict__ riu,
                         const int* __restrict__ ruu,
                         int* __restrict__ cui, int* __restrict__ ciu, int* __restrict__ cuu,
                         int* __restrict__ lui, int* __restrict__ liu, int* __restrict__ luu) {
  int gid = blockIdx.x * blockDim.x + threadIdx.x;
  int st = gridDim.x * blockDim.x;
  for (int e = gid; e < NE; e += st) {
    int d = eui[NE + e];
    lui[rui[d] + atomicAdd(&cui[d], 1)] = eui[e];
  }
  for (int e = gid; e < NE; e += st) {
    int d = eiu[NE + e];
    liu[riu[d] + atomicAdd(&ciu[d], 1)] = eiu[e];
  }
  for (int e = gid; e < NE; e += st) {
    int d = euu[NE + e];
    luu[ruu[d] + atomicAdd(&cuu[d], 1)] = euu[e];
  }
}

// ---------------- weight prep: bf16 B^T, packed per layer ----------------
__global__ void prep_w(const float* __restrict__ Wl, const float* __restrict__ Wr,
                       ushort* __restrict__ BtU, ushort* __restrict__ BtI) {
  int i = blockIdx.x * blockDim.x + threadIdx.x;
  const int nU = 2 * C * 384;
  const int nI = 2 * C * 256;
  if (i < nU) {
    int l = i / (C * 384); int rem = i - l * (C * 384);
    int n = rem / 384; int kt = rem - n * 384;
    float v;
    if (kt < 128)       v = Wl[((size_t)(l * 3 + 1) * C + kt) * C + n];
    else if (kt < 256)  v = Wl[((size_t)(l * 3 + 2) * C + (kt - 128)) * C + n];
    else                v = Wr[((size_t)(l * 3 + 1) * C + (kt - 256)) * C + n]
                          + Wr[((size_t)(l * 3 + 2) * C + (kt - 256)) * C + n];
    BtU[i] = f2bf(v);
  } else if (i < nU + nI) {
    int j = i - nU;
    int l = j / (C * 256); int rem = j - l * (C * 256);
    int n = rem / 256; int kt = rem - n * 256;
    float v = (kt < 128) ? Wl[((size_t)(l * 3 + 0) * C + kt) * C + n]
                         : Wr[((size_t)(l * 3 + 0) * C + (kt - 128)) * C + n];
    BtI[j] = f2bf(v);
  }
}

// ---------------- merged mean aggregation: one wave per dst, 4 edges/iter, MLP x2 ----------
__global__ __launch_bounds__(256) void agg_all(
    const ushort* __restrict__ xub, const ushort* __restrict__ xib,
    const int* __restrict__ rpui, const int* __restrict__ elui, ushort* __restrict__ mui,
    const int* __restrict__ rpiu, const int* __restrict__ eliu, ushort* __restrict__ miu,
    const int* __restrict__ rpuu, const int* __restrict__ eluu, ushort* __restrict__ muu) {
  int gw = (blockIdx.x * blockDim.x + threadIdx.x) >> 6;
  int lane = threadIdx.x & 63;
  const ushort* x; const int* rp; const int* el; ushort* m; int d;
  if (gw < NI)             { x = xub; rp = rpui; el = elui; m = mui; d = gw; }
  else if (gw < NI + NU)   { x = xib; rp = rpiu; el = eliu; m = miu; d = gw - NI; }
  else if (gw < NI + 2*NU) { x = xub; rp = rpuu; el = eluu; m = muu; d = gw - NI - NU; }
  else return;
  int beg = rp[d], end = rp[d + 1];
  int n = end - beg;
  int q = lane >> 4, cg = lane & 15;   // quarter (edge slot), channel group
  float acc[8] = {0.f, 0.f, 0.f, 0.f, 0.f, 0.f, 0.f, 0.f};

  for (int base = 0; base < n; base += 64) {
    // one coalesced load of up to 64 source ids
    int idx = base + lane;
    int sid = el[beg + (idx < n ? idx : n - 1)];
    int iters = min(64, n - base);
    for (int t0 = 0; t0 < iters; t0 += 8) {
      int t1 = t0 + q, t2 = t0 + 4 + q;
      int s1 = __shfl(sid, t1 < iters ? t1 : iters - 1, 64);
      int s2 = __shfl(sid, t2 < iters ? t2 : iters - 1, 64);
      // two independent 16B/lane gathers in flight (each quarter covers one 256B row)
      bf16x8 v1 = *(const bf16x8*)&x[(size_t)s1 * C + cg * 8];
      bf16x8 v2 = *(const bf16x8*)&x[(size_t)s2 * C + cg * 8];
      bool b1 = t1 < iters, b2 = t2 < iters;
#pragma unroll
      for (int k = 0; k < 8; ++k) {
        acc[k] += b1 ? bf2f((ushort)v1[k]) : 0.f;
        acc[k] += b2 ? bf2f((ushort)v2[k]) : 0.f;
      }
    }
  }
  // combine the 4 quarters (butterfly over lane bits 4,5)
#pragma unroll
  for (int k = 0; k < 8; ++k) {
    acc[k] += __shfl_xor(acc[k], 16, 64);
    acc[k] += __shfl_xor(acc[k], 32, 64);
  }
  float inv = 1.0f / (float)(n > 0 ? n : 1);
  if (q == 0) {
    bf16x8 r;
#pragma unroll
    for (int k = 0; k < 8; ++k) r[k] = (short)f2bf(acc[k] * inv);
    *(bf16x8*)&m[(size_t)d * C + cg * 8] = r;
  }
}

// ---------------- fused MFMA GEMM + bias + LayerNorm + ReLU (user & item in one grid) --------
struct GemmParams {
  const ushort *Au0, *Au1, *Au2, *BtU;
  const float  *bu0, *bu1, *lnwU, *lnbU;
  float* outU;
  const ushort *Ai0, *Ai1, *BtI;
  const float  *bi0, *lnwI, *lnbI;
  float* outI;
  ushort *outUb, *outIb;   // optional bf16 copies (next layer's tables)
  int gbU;
};

__global__ __launch_bounds__(256) void gemm_mfma_ln(GemmParams p) {
  __shared__ __align__(16) char smem[16384];
  char* Al = smem;            // A tile: 128 rows x 32 k (bf16), swizzled, 64B/row
  char* Bl = smem + 8192;     // B tile: 128 cols x 32 k (bf16), swizzled
  int tid = threadIdx.x;
  bool isU = (int)blockIdx.x < p.gbU;
  const ushort* Aseg[3]; const ushort* Bt; int KT, M;
  const float *bias0, *bias1, *lnw, *lnb; float* outp; ushort* outb;
  if (isU) {
    Aseg[0] = p.Au0; Aseg[1] = p.Au1; Aseg[2] = p.Au2; Bt = p.BtU; KT = 384; M = NU;
    bias0 = p.bu0; bias1 = p.bu1; lnw = p.lnwU; lnb = p.lnbU; outp = p.outU; outb = p.outUb;
  } else {
    Aseg[0] = p.Ai0; Aseg[1] = p.Ai1; Aseg[2] = p.Ai1; Bt = p.BtI; KT = 256; M = NI;
    bias0 = p.bi0; bias1 = nullptr; lnw = p.lnwI; lnb = p.lnbI; outp = p.outI; outb = p.outIb;
  }
  int row0 = (isU ? (int)blockIdx.x : (int)blockIdx.x - p.gbU) * BM;

  int w = tid >> 6, lane = tid & 63;
  int l15 = lane & 15, l4 = lane >> 4;
  int srow = tid >> 1, shalf = tid & 1;           // staging: 2 threads per row/col
  int s0 = shalf * 2;
  int sw = ((srow >> 1) & 3) << 4;                // swizzle bits for staging row

  int abyte[2], bbyte[8];
#pragma unroll
  for (int r = 0; r < 2; ++r) {
    int row = w * 32 + r * 16 + l15;
    abyte[r] = row * 64 + (((l4 << 4)) ^ (((row >> 1) & 3) << 4));
  }
#pragma unroll
  for (int c = 0; c < 8; ++c) {
    int col = c * 16 + l15;
    bbyte[c] = col * 64 + (((l4 << 4)) ^ (((col >> 1) & 3) << 4));
  }

  f32x4 acc[2][8];
#pragma unroll
  for (int r = 0; r < 2; ++r)
#pragma unroll
    for (int c = 0; c < 8; ++c) acc[r][c] = (f32x4){0.f, 0.f, 0.f, 0.f};

  for (int kt0 = 0; kt0 < KT; kt0 += 32) {
    int seg = kt0 >> 7, kin = kt0 & 127;
    const ushort* Ag = Aseg[seg];
    int gr = row0 + srow;
    bf16x8 va0 = {}, va1 = {};
    if (gr < M) {
      const ushort* ga = Ag + (size_t)gr * C + kin + shalf * 16;
      va0 = *(const bf16x8*)(ga);
      va1 = *(const bf16x8*)(ga + 8);
    }
    *(bf16x8*)(Al + srow * 64 + ((s0 << 4) ^ sw))       = va0;
    *(bf16x8*)(Al + srow * 64 + (((s0 + 1) << 4) ^ sw)) = va1;
    const ushort* gb = Bt + (size_t)srow * KT + kt0 + shalf * 16;
    bf16x8 vb0 = *(const bf16x8*)(gb);
    bf16x8 vb1 = *(const bf16x8*)(gb + 8);
    *(bf16x8*)(Bl + srow * 64 + ((s0 << 4) ^ sw))       = vb0;
    *(bf16x8*)(Bl + srow * 64 + (((s0 + 1) << 4) ^ sw)) = vb1;
    __syncthreads();

    bf16x8 af[2], bfr[8];
#pragma unroll
    for (int r = 0; r < 2; ++r) af[r] = *(const bf16x8*)(Al + abyte[r]);
#pragma unroll
    for (int c = 0; c < 8; ++c) bfr[c] = *(const bf16x8*)(Bl + bbyte[c]);
#pragma unroll
    for (int r = 0; r < 2; ++r)
#pragma unroll
      for (int c = 0; c < 8; ++c)
        acc[r][c] = __builtin_amdgcn_mfma_f32_16x16x32_bf16(af[r], bfr[c], acc[r][c], 0, 0, 0);
    __syncthreads();
  }

  float bj[8], wv[8], bvv[8];
#pragma unroll
  for (int c = 0; c < 8; ++c) {
    int col = c * 16 + l15;
    bj[c]  = bias0[col] + (bias1 ? bias1[col] : 0.f);
    wv[c]  = lnw[col];
    bvv[c] = lnb[col];
  }
#pragma unroll
  for (int r = 0; r < 2; ++r) {
#pragma unroll
    for (int i = 0; i < 4; ++i) {
      float v[8];
#pragma unroll
      for (int c = 0; c < 8; ++c) v[c] = acc[r][c][i] + bj[c];
      float s = 0.f;
#pragma unroll
      for (int c = 0; c < 8; ++c) s += v[c];
      s += __shfl_xor(s, 1, 64);
      s += __shfl_xor(s, 2, 64);
      s += __shfl_xor(s, 4, 64);
      s += __shfl_xor(s, 8, 64);
      float mu = s * (1.0f / C);
      float var = 0.f;
#pragma unroll
      for (int c = 0; c < 8; ++c) { float dd = v[c] - mu; var = fmaf(dd, dd, var); }
      var += __shfl_xor(var, 1, 64);
      var += __shfl_xor(var, 2, 64);
      var += __shfl_xor(var, 4, 64);
      var += __shfl_xor(var, 8, 64);
      float rs = rsqrtf(var * (1.0f / C) + 1e-5f);
      int grow = row0 + w * 32 + r * 16 + l4 * 4 + i;
      if (grow < M) {
#pragma unroll
        for (int c = 0; c < 8; ++c) {
          float y = (v[c] - mu) * rs * wv[c] + bvv[c];
          y = y > 0.f ? y : 0.f;
          outp[(size_t)grow * C + c * 16 + l15] = y;
          if (outb) outb[(size_t)grow * C + c * 16 + l15] = f2bf(y);
        }
      }
    }
  }
}

extern "C" void kernel_launch(void* const* d_in, const int* in_sizes, int n_in,
                              void* d_out, int out_size, void* d_ws, size_t ws_size,
                              hipStream_t stream) {
  (void)in_sizes; (void)n_in; (void)out_size;
  const float* xu0 = (const float*)d_in[0];
  const float* xi0 = (const float*)d_in[1];
  const int* eui = (const int*)d_in[2];
  const int* eiu = (const int*)d_in[3];
  const int* euu = (const int*)d_in[4];
  const float* Wl = (const float*)d_in[5];
  const float* bl = (const float*)d_in[6];
  const float* Wr = (const float*)d_in[7];
  const float* lnw = (const float*)d_in[8];
  const float* lnb = (const float*)d_in[9];
  float* out_u = (float*)d_out;
  float* out_i = (float*)d_out + (size_t)NU * C;

  char* w = (char*)d_ws;
  size_t used = 0;
  auto alloc = [&](size_t bytes) {
    char* p = w; size_t pad = (bytes + 255) & ~(size_t)255;
    w += pad; used += pad; return p;
  };
  ushort* x0ub = (ushort*)alloc((size_t)NU * C * 2);
  ushort* x0ib = (ushort*)alloc((size_t)NI * C * 2);
  ushort* x1ub = (ushort*)alloc((size_t)NU * C * 2);
  ushort* x1ib = (ushort*)alloc((size_t)NI * C * 2);
  ushort* mui  = (ushort*)alloc((size_t)NI * C * 2);
  ushort* miu  = (ushort*)alloc((size_t)NU * C * 2);
  ushort* muu  = (ushort*)alloc((size_t)NU * C * 2);
  int* rp_ui = (int*)alloc((NI + 1) * 4);
  int* rp_iu = (int*)alloc((NU + 1) * 4);
  int* rp_uu = (int*)alloc((NU + 1) * 4);
  int* el_ui = (int*)alloc((size_t)NE * 4);
  int* el_iu = (int*)alloc((size_t)NE * 4);
  int* el_uu = (int*)alloc((size_t)NE * 4);
  int* cur = (int*)alloc((size_t)3 * NU * 4);
  int* cur_ui = cur; int* cur_iu = cur + NU; int* cur_uu = cur + 2 * NU;
  ushort* BtU = (ushort*)alloc((size_t)2 * C * 384 * 2);
  ushort* BtI = (ushort*)alloc((size_t)2 * C * 256 * 2);

  if (used > ws_size) return;   // clean failure instead of OOB crash

  hipMemsetAsync(cur, 0, (size_t)3 * NU * 4, stream);
  conv2bf<<<2048, 256, 0, stream>>>(xu0, x0ub, xi0, x0ib, NU * C / 4);
  count_all<<<2048, 256, 0, stream>>>(eui, eiu, euu, cur_ui, cur_iu, cur_uu);
  scan3<<<3, 256, 0, stream>>>(cur_ui, rp_ui, cur_iu, rp_iu, cur_uu, rp_uu);
  fill_all<<<2048, 256, 0, stream>>>(eui, eiu, euu, rp_ui, rp_iu, rp_uu,
                                     cur_ui, cur_iu, cur_uu, el_ui, el_iu, el_uu);
  prep_w<<<(2 * C * 384 + 2 * C * 256 + 255) / 256, 256, 0, stream>>>(Wl, Wr, BtU, BtI);

  int gbU = (NU + BM - 1) / BM;   // 782
  int gbI = (NI + BM - 1) / BM;   // 782
  int aggBlocks = (NI + 2 * NU) / 4;  // one wave per dst, 4 waves/block

  for (int l = 0; l < 2; ++l) {
    const ushort* xub = l ? x1ub : x0ub;
    const ushort* xib = l ? x1ib : x0ib;
    agg_all<<<aggBlocks, 256, 0, stream>>>(xub, xib,
        rp_ui, el_ui, mui, rp_iu, el_iu, miu, rp_uu, el_uu, muu);
    GemmParams p;
    p.Au0 = miu; p.Au1 = muu; p.Au2 = xub; p.BtU = BtU + (size_t)l * C * 384;
    p.bu0 = bl + (l * 3 + 1) * C; p.bu1 = bl + (l * 3 + 2) * C;
    p.lnwU = lnw + (l * 2 + 0) * C; p.lnbU = lnb + (l * 2 + 0) * C; p.outU = out_u;
    p.Ai0 = mui; p.Ai1 = xib; p.BtI = BtI + (size_t)l * C * 256;
    p.bi0 = bl + (l * 3 + 0) * C;
    p.lnwI = lnw + (l * 2 + 1) * C; p.lnbI = lnb + (l * 2 + 1) * C; p.outI = out_i;
    p.outUb = (l == 0) ? x1ub : nullptr;
    p.outIb = (l == 0) ? x1ib : nullptr;
    p.gbU = gbU;
    gemm_mfma_ln<<<gbU + gbI, 256, 0, stream>>>(p);
  }
}

// Round 5
// 811.472 us; speedup vs baseline: 2.6521x; 1.2058x over previous
//
#include <hip/hip_runtime.h>

#define NU 100000
#define NI 100000
#define NE 1000000
#define C  128
#define CC (C*C)
#define BM 128
#define SCHUNK 2048
#define NCHUNK 49   // ceil(100000 / 2048)

typedef unsigned int uint;
typedef unsigned short ushort;
using bf16x8 = __attribute__((ext_vector_type(8))) short;
using f32x4  = __attribute__((ext_vector_type(4))) float;

__device__ __forceinline__ ushort f2bf(float f) {
  uint u = __builtin_bit_cast(uint, f);
  u = (u + 0x7fffu + ((u >> 16) & 1u)) >> 16;   // RNE
  return (ushort)u;
}
__device__ __forceinline__ float bf2f(ushort h) {
  return __builtin_bit_cast(float, (uint)h << 16);
}

// ---------------- f32 -> bf16 table conversion (two tables per call) ----------------
__global__ void conv2bf(const float* __restrict__ a, ushort* __restrict__ ab,
                        const float* __restrict__ b, ushort* __restrict__ bb, int n4) {
  int i = blockIdx.x * blockDim.x + threadIdx.x;
  int st = gridDim.x * blockDim.x;
  for (; i < n4; i += st) {
    float4 va = ((const float4*)a)[i];
    ushort4 ra; ra.x = f2bf(va.x); ra.y = f2bf(va.y); ra.z = f2bf(va.z); ra.w = f2bf(va.w);
    ((ushort4*)ab)[i] = ra;
    float4 vb = ((const float4*)b)[i];
    ushort4 rb; rb.x = f2bf(vb.x); rb.y = f2bf(vb.y); rb.z = f2bf(vb.z); rb.w = f2bf(vb.w);
    ((ushort4*)bb)[i] = rb;
  }
}

// ---------------- CSR build ----------------
__global__ void count_all(const int* __restrict__ eui, const int* __restrict__ eiu,
                          const int* __restrict__ euu,
                          int* __restrict__ cui, int* __restrict__ ciu, int* __restrict__ cuu) {
  int gid = blockIdx.x * blockDim.x + threadIdx.x;
  int st = gridDim.x * blockDim.x;
  for (int e = gid; e < NE; e += st) atomicAdd(&cui[eui[NE + e]], 1);
  for (int e = gid; e < NE; e += st) atomicAdd(&ciu[eiu[NE + e]], 1);
  for (int e = gid; e < NE; e += st) atomicAdd(&cuu[euu[NE + e]], 1);
}

// ---------------- parallel 3-phase scan over the 3 count arrays (N=100000 each) ---------
// A: per-chunk sums. 3*NCHUNK blocks; block b: type b/NCHUNK, chunk b%NCHUNK.
__global__ void scan_a(const int* __restrict__ c0, const int* __restrict__ c1,
                       const int* __restrict__ c2, int* __restrict__ chunksum) {
  const int N = 100000;
  int t = blockIdx.x / NCHUNK, ch = blockIdx.x - t * NCHUNK;
  const int* cnt = t == 0 ? c0 : (t == 1 ? c1 : c2);
  int base = ch * SCHUNK;
  int tid = threadIdx.x, lane = tid & 63, w = tid >> 6;
  __shared__ int wsum[4];
  int idx0 = base + tid * 8;
  int s = 0;
#pragma unroll
  for (int i = 0; i < 8; ++i) s += (idx0 + i < N) ? cnt[idx0 + i] : 0;
#pragma unroll
  for (int d = 1; d < 64; d <<= 1) s += __shfl_xor(s, d, 64);
  if (lane == 0) wsum[w] = s;
  __syncthreads();
  if (tid == 0) chunksum[blockIdx.x] = wsum[0] + wsum[1] + wsum[2] + wsum[3];
}

// B: one block; wave w (w<3) exclusive-scans its type's NCHUNK chunk sums.
__global__ void scan_b(const int* __restrict__ chunksum, int* __restrict__ chunkoff,
                       int* __restrict__ r0, int* __restrict__ r1, int* __restrict__ r2) {
  const int N = 100000;
  int tid = threadIdx.x, lane = tid & 63, w = tid >> 6;
  if (w >= 3) return;
  int v = (lane < NCHUNK) ? chunksum[w * NCHUNK + lane] : 0;
  int inc = v;
#pragma unroll
  for (int d = 1; d < 64; d <<= 1) {
    int u = __shfl_up(inc, d, 64);
    if (lane >= d) inc += u;
  }
  if (lane < NCHUNK) chunkoff[w * NCHUNK + lane] = inc - v;
  if (lane == NCHUNK - 1) {
    int* rp = w == 0 ? r0 : (w == 1 ? r1 : r2);
    rp[N] = inc;  // total
  }
}

// C: intra-chunk exclusive scan + emit rowptr AND cursor(=rowptr).
__global__ void scan_c(const int* __restrict__ c0, const int* __restrict__ c1,
                       const int* __restrict__ c2,
                       int* __restrict__ r0, int* __restrict__ r1, int* __restrict__ r2,
                       int* __restrict__ k0, int* __restrict__ k1, int* __restrict__ k2,
                       const int* __restrict__ chunkoff) {
  const int N = 100000;
  int t = blockIdx.x / NCHUNK, ch = blockIdx.x - t * NCHUNK;
  const int* cnt = t == 0 ? c0 : (t == 1 ? c1 : c2);
  int* rowptr    = t == 0 ? r0 : (t == 1 ? r1 : r2);
  int* cur       = t == 0 ? k0 : (t == 1 ? k1 : k2);
  int base = ch * SCHUNK;
  int tid = threadIdx.x, lane = tid & 63, w = tid >> 6;
  __shared__ int wls[4];
  int idx0 = base + tid * 8;
  int c[8], pre[8];
  int tsum = 0;
#pragma unroll
  for (int i = 0; i < 8; ++i) {
    c[i] = (idx0 + i < N) ? cnt[idx0 + i] : 0;
    pre[i] = tsum; tsum += c[i];
  }
  int inc = tsum;
#pragma unroll
  for (int d = 1; d < 64; d <<= 1) {
    int u = __shfl_up(inc, d, 64);
    if (lane >= d) inc += u;
  }
  if (lane == 63) wls[w] = inc;
  __syncthreads();
  int wbase = 0;
#pragma unroll
  for (int ww = 0; ww < 4; ++ww) { if (ww < w) wbase += wls[ww]; }
  int toff = chunkoff[blockIdx.x] + wbase + (inc - tsum);
#pragma unroll
  for (int i = 0; i < 8; ++i)
    if (idx0 + i < N) { int v = toff + pre[i]; rowptr[idx0 + i] = v; cur[idx0 + i] = v; }
}

// ---------------- fill: dst-range partitioned (8 groups ~ XCDs), cursor-only ------------
__global__ void fill_all(const int* __restrict__ eui, const int* __restrict__ eiu,
                         const int* __restrict__ euu,
                         int* __restrict__ cui, int* __restrict__ ciu, int* __restrict__ cuu,
                         int* __restrict__ lui, int* __restrict__ liu, int* __restrict__ luu) {
  int grp = blockIdx.x & 7;            // dst-range group (~XCD under round-robin dispatch)
  int bid = blockIdx.x >> 3;
  int nb  = gridDim.x >> 3;
  int lo = grp * 12500, hi = lo + 12500;   // 100000/8
  int gid = bid * blockDim.x + threadIdx.x;
  int st  = nb * blockDim.x;
  for (int e = gid; e < NE; e += st) {
    int d = eui[NE + e];
    if (d >= lo && d < hi) lui[atomicAdd(&cui[d], 1)] = eui[e];
  }
  for (int e = gid; e < NE; e += st) {
    int d = eiu[NE + e];
    if (d >= lo && d < hi) liu[atomicAdd(&ciu[d], 1)] = eiu[e];
  }
  for (int e = gid; e < NE; e += st) {
    int d = euu[NE + e];
    if (d >= lo && d < hi) luu[atomicAdd(&cuu[d], 1)] = euu[e];
  }
}

// ---------------- weight prep: bf16 B^T, packed per layer ----------------
__global__ void prep_w(const float* __restrict__ Wl, const float* __restrict__ Wr,
                       ushort* __restrict__ BtU, ushort* __restrict__ BtI) {
  int i = blockIdx.x * blockDim.x + threadIdx.x;
  const int nU = 2 * C * 384;
  const int nI = 2 * C * 256;
  if (i < nU) {
    int l = i / (C * 384); int rem = i - l * (C * 384);
    int n = rem / 384; int kt = rem - n * 384;
    float v;
    if (kt < 128)       v = Wl[((size_t)(l * 3 + 1) * C + kt) * C + n];
    else if (kt < 256)  v = Wl[((size_t)(l * 3 + 2) * C + (kt - 128)) * C + n];
    else                v = Wr[((size_t)(l * 3 + 1) * C + (kt - 256)) * C + n]
                          + Wr[((size_t)(l * 3 + 2) * C + (kt - 256)) * C + n];
    BtU[i] = f2bf(v);
  } else if (i < nU + nI) {
    int j = i - nU;
    int l = j / (C * 256); int rem = j - l * (C * 256);
    int n = rem / 256; int kt = rem - n * 256;
    float v = (kt < 128) ? Wl[((size_t)(l * 3 + 0) * C + kt) * C + n]
                         : Wr[((size_t)(l * 3 + 0) * C + (kt - 128)) * C + n];
    BtI[j] = f2bf(v);
  }
}

// ---------------- merged mean aggregation: one wave per dst, 4 gathers in flight --------
__global__ __launch_bounds__(256) void agg_all(
    const ushort* __restrict__ xub, const ushort* __restrict__ xib,
    const int* __restrict__ rpui, const int* __restrict__ elui, ushort* __restrict__ mui,
    const int* __restrict__ rpiu, const int* __restrict__ eliu, ushort* __restrict__ miu,
    const int* __restrict__ rpuu, const int* __restrict__ eluu, ushort* __restrict__ muu) {
  int gw = (blockIdx.x * blockDim.x + threadIdx.x) >> 6;
  int lane = threadIdx.x & 63;
  const ushort* x; const int* rp; const int* el; ushort* m; int d;
  if (gw < NI)             { x = xub; rp = rpui; el = elui; m = mui; d = gw; }
  else if (gw < NI + NU)   { x = xib; rp = rpiu; el = eliu; m = miu; d = gw - NI; }
  else if (gw < NI + 2*NU) { x = xub; rp = rpuu; el = eluu; m = muu; d = gw - NI - NU; }
  else return;
  int beg = rp[d], end = rp[d + 1];
  int n = end - beg;
  int q = lane >> 4, cg = lane & 15;   // quarter (edge slot), channel group
  float acc[8] = {0.f, 0.f, 0.f, 0.f, 0.f, 0.f, 0.f, 0.f};

  for (int base = 0; base < n; base += 64) {
    int idx = base + lane;
    int sid = el[beg + (idx < n ? idx : n - 1)];
    int iters = min(64, n - base);
    for (int t0 = 0; t0 < iters; t0 += 16) {
#pragma unroll
      for (int u = 0; u < 4; ++u) {
        int t = t0 + u * 4 + q;
        int s = __shfl(sid, t < 64 ? t : 63, 64);
        if (t < iters) {   // predicated: inactive lanes issue no gather
          bf16x8 v = *(const bf16x8*)&x[(size_t)s * C + cg * 8];
#pragma unroll
          for (int k = 0; k < 8; ++k) acc[k] += bf2f((ushort)v[k]);
        }
      }
    }
  }
#pragma unroll
  for (int k = 0; k < 8; ++k) {
    acc[k] += __shfl_xor(acc[k], 16, 64);
    acc[k] += __shfl_xor(acc[k], 32, 64);
  }
  float inv = 1.0f / (float)(n > 0 ? n : 1);
  if (q == 0) {
    bf16x8 r;
#pragma unroll
    for (int k = 0; k < 8; ++k) r[k] = (short)f2bf(acc[k] * inv);
    *(bf16x8*)&m[(size_t)d * C + cg * 8] = r;
  }
}

// ---------------- fused MFMA GEMM + bias + LayerNorm + ReLU (user & item in one grid) --------
struct GemmParams {
  const ushort *Au0, *Au1, *Au2, *BtU;
  const float  *bu0, *bu1, *lnwU, *lnbU;
  float* outU;
  const ushort *Ai0, *Ai1, *BtI;
  const float  *bi0, *lnwI, *lnbI;
  float* outI;
  ushort *outUb, *outIb;   // optional bf16 copies (next layer's tables)
  int gbU;
};

__global__ __launch_bounds__(256) void gemm_mfma_ln(GemmParams p) {
  __shared__ __align__(16) char smem[16384];
  char* Al = smem;            // A tile: 128 rows x 32 k (bf16), swizzled, 64B/row
  char* Bl = smem + 8192;     // B tile: 128 cols x 32 k (bf16), swizzled
  int tid = threadIdx.x;
  bool isU = (int)blockIdx.x < p.gbU;
  const ushort* Aseg[3]; const ushort* Bt; int KT, M;
  const float *bias0, *bias1, *lnw, *lnb; float* outp; ushort* outb;
  if (isU) {
    Aseg[0] = p.Au0; Aseg[1] = p.Au1; Aseg[2] = p.Au2; Bt = p.BtU; KT = 384; M = NU;
    bias0 = p.bu0; bias1 = p.bu1; lnw = p.lnwU; lnb = p.lnbU; outp = p.outU; outb = p.outUb;
  } else {
    Aseg[0] = p.Ai0; Aseg[1] = p.Ai1; Aseg[2] = p.Ai1; Bt = p.BtI; KT = 256; M = NI;
    bias0 = p.bi0; bias1 = nullptr; lnw = p.lnwI; lnb = p.lnbI; outp = p.outI; outb = p.outIb;
  }
  int row0 = (isU ? (int)blockIdx.x : (int)blockIdx.x - p.gbU) * BM;

  int w = tid >> 6, lane = tid & 63;
  int l15 = lane & 15, l4 = lane >> 4;
  int srow = tid >> 1, shalf = tid & 1;           // staging: 2 threads per row/col
  int s0 = shalf * 2;
  int sw = ((srow >> 1) & 3) << 4;                // swizzle bits for staging row

  int abyte[2], bbyte[8];
#pragma unroll
  for (int r = 0; r < 2; ++r) {
    int row = w * 32 + r * 16 + l15;
    abyte[r] = row * 64 + (((l4 << 4)) ^ (((row >> 1) & 3) << 4));
  }
#pragma unroll
  for (int c = 0; c < 8; ++c) {
    int col = c * 16 + l15;
    bbyte[c] = col * 64 + (((l4 << 4)) ^ (((col >> 1) & 3) << 4));
  }

  f32x4 acc[2][8];
#pragma unroll
  for (int r = 0; r < 2; ++r)
#pragma unroll
    for (int c = 0; c < 8; ++c) acc[r][c] = (f32x4){0.f, 0.f, 0.f, 0.f};

  for (int kt0 = 0; kt0 < KT; kt0 += 32) {
    int seg = kt0 >> 7, kin = kt0 & 127;
    const ushort* Ag = Aseg[seg];
    int gr = row0 + srow;
    bf16x8 va0 = {}, va1 = {};
    if (gr < M) {
      const ushort* ga = Ag + (size_t)gr * C + kin + shalf * 16;
      va0 = *(const bf16x8*)(ga);
      va1 = *(const bf16x8*)(ga + 8);
    }
    *(bf16x8*)(Al + srow * 64 + ((s0 << 4) ^ sw))       = va0;
    *(bf16x8*)(Al + srow * 64 + (((s0 + 1) << 4) ^ sw)) = va1;
    const ushort* gb = Bt + (size_t)srow * KT + kt0 + shalf * 16;
    bf16x8 vb0 = *(const bf16x8*)(gb);
    bf16x8 vb1 = *(const bf16x8*)(gb + 8);
    *(bf16x8*)(Bl + srow * 64 + ((s0 << 4) ^ sw))       = vb0;
    *(bf16x8*)(Bl + srow * 64 + (((s0 + 1) << 4) ^ sw)) = vb1;
    __syncthreads();

    bf16x8 af[2], bfr[8];
#pragma unroll
    for (int r = 0; r < 2; ++r) af[r] = *(const bf16x8*)(Al + abyte[r]);
#pragma unroll
    for (int c = 0; c < 8; ++c) bfr[c] = *(const bf16x8*)(Bl + bbyte[c]);
#pragma unroll
    for (int r = 0; r < 2; ++r)
#pragma unroll
      for (int c = 0; c < 8; ++c)
        acc[r][c] = __builtin_amdgcn_mfma_f32_16x16x32_bf16(af[r], bfr[c], acc[r][c], 0, 0, 0);
    __syncthreads();
  }

  float bj[8], wv[8], bvv[8];
#pragma unroll
  for (int c = 0; c < 8; ++c) {
    int col = c * 16 + l15;
    bj[c]  = bias0[col] + (bias1 ? bias1[col] : 0.f);
    wv[c]  = lnw[col];
    bvv[c] = lnb[col];
  }
#pragma unroll
  for (int r = 0; r < 2; ++r) {
#pragma unroll
    for (int i = 0; i < 4; ++i) {
      float v[8];
#pragma unroll
      for (int c = 0; c < 8; ++c) v[c] = acc[r][c][i] + bj[c];
      float s = 0.f;
#pragma unroll
      for (int c = 0; c < 8; ++c) s += v[c];
      s += __shfl_xor(s, 1, 64);
      s += __shfl_xor(s, 2, 64);
      s += __shfl_xor(s, 4, 64);
      s += __shfl_xor(s, 8, 64);
      float mu = s * (1.0f / C);
      float var = 0.f;
#pragma unroll
      for (int c = 0; c < 8; ++c) { float dd = v[c] - mu; var = fmaf(dd, dd, var); }
      var += __shfl_xor(var, 1, 64);
      var += __shfl_xor(var, 2, 64);
      var += __shfl_xor(var, 4, 64);
      var += __shfl_xor(var, 8, 64);
      float rs = rsqrtf(var * (1.0f / C) + 1e-5f);
      int grow = row0 + w * 32 + r * 16 + l4 * 4 + i;
      if (grow < M) {
#pragma unroll
        for (int c = 0; c < 8; ++c) {
          float y = (v[c] - mu) * rs * wv[c] + bvv[c];
          y = y > 0.f ? y : 0.f;
          outp[(size_t)grow * C + c * 16 + l15] = y;
          if (outb) outb[(size_t)grow * C + c * 16 + l15] = f2bf(y);
        }
      }
    }
  }
}

extern "C" void kernel_launch(void* const* d_in, const int* in_sizes, int n_in,
                              void* d_out, int out_size, void* d_ws, size_t ws_size,
                              hipStream_t stream) {
  (void)in_sizes; (void)n_in; (void)out_size;
  const float* xu0 = (const float*)d_in[0];
  const float* xi0 = (const float*)d_in[1];
  const int* eui = (const int*)d_in[2];
  const int* eiu = (const int*)d_in[3];
  const int* euu = (const int*)d_in[4];
  const float* Wl = (const float*)d_in[5];
  const float* bl = (const float*)d_in[6];
  const float* Wr = (const float*)d_in[7];
  const float* lnw = (const float*)d_in[8];
  const float* lnb = (const float*)d_in[9];
  float* out_u = (float*)d_out;
  float* out_i = (float*)d_out + (size_t)NU * C;

  char* w = (char*)d_ws;
  size_t used = 0;
  auto alloc = [&](size_t bytes) {
    char* p = w; size_t pad = (bytes + 255) & ~(size_t)255;
    w += pad; used += pad; return p;
  };
  ushort* x0ub = (ushort*)alloc((size_t)NU * C * 2);
  ushort* x0ib = (ushort*)alloc((size_t)NI * C * 2);
  ushort* x1ub = (ushort*)alloc((size_t)NU * C * 2);
  ushort* x1ib = (ushort*)alloc((size_t)NI * C * 2);
  ushort* mui  = (ushort*)alloc((size_t)NI * C * 2);
  ushort* miu  = (ushort*)alloc((size_t)NU * C * 2);
  ushort* muu  = (ushort*)alloc((size_t)NU * C * 2);
  int* rp_ui = (int*)alloc((NI + 1) * 4);
  int* rp_iu = (int*)alloc((NU + 1) * 4);
  int* rp_uu = (int*)alloc((NU + 1) * 4);
  int* el_ui = (int*)alloc((size_t)NE * 4);
  int* el_iu = (int*)alloc((size_t)NE * 4);
  int* el_uu = (int*)alloc((size_t)NE * 4);
  int* cur = (int*)alloc((size_t)3 * NU * 4);
  int* cur_ui = cur; int* cur_iu = cur + NU; int* cur_uu = cur + 2 * NU;
  ushort* BtU = (ushort*)alloc((size_t)2 * C * 384 * 2);
  ushort* BtI = (ushort*)alloc((size_t)2 * C * 256 * 2);
  int* chunksum = (int*)alloc(3 * NCHUNK * 4);
  int* chunkoff = (int*)alloc(3 * NCHUNK * 4);

  if (used > ws_size) return;   // clean failure instead of OOB crash

  hipMemsetAsync(cur, 0, (size_t)3 * NU * 4, stream);
  conv2bf<<<2048, 256, 0, stream>>>(xu0, x0ub, xi0, x0ib, NU * C / 4);
  count_all<<<2048, 256, 0, stream>>>(eui, eiu, euu, cur_ui, cur_iu, cur_uu);
  scan_a<<<3 * NCHUNK, 256, 0, stream>>>(cur_ui, cur_iu, cur_uu, chunksum);
  scan_b<<<1, 256, 0, stream>>>(chunksum, chunkoff, rp_ui, rp_iu, rp_uu);
  scan_c<<<3 * NCHUNK, 256, 0, stream>>>(cur_ui, cur_iu, cur_uu,
                                         rp_ui, rp_iu, rp_uu,
                                         cur_ui, cur_iu, cur_uu, chunkoff);
  fill_all<<<2048, 256, 0, stream>>>(eui, eiu, euu,
                                     cur_ui, cur_iu, cur_uu, el_ui, el_iu, el_uu);
  prep_w<<<(2 * C * 384 + 2 * C * 256 + 255) / 256, 256, 0, stream>>>(Wl, Wr, BtU, BtI);

  int gbU = (NU + BM - 1) / BM;   // 782
  int gbI = (NI + BM - 1) / BM;   // 782
  int aggBlocks = (NI + 2 * NU) / 4;  // one wave per dst, 4 waves/block

  for (int l = 0; l < 2; ++l) {
    const ushort* xub = l ? x1ub : x0ub;
    const ushort* xib = l ? x1ib : x0ib;
    agg_all<<<aggBlocks, 256, 0, stream>>>(xub, xib,
        rp_ui, el_ui, mui, rp_iu, el_iu, miu, rp_uu, el_uu, muu);
    GemmParams p;
    p.Au0 = miu; p.Au1 = muu; p.Au2 = xub; p.BtU = BtU + (size_t)l * C * 384;
    p.bu0 = bl + (l * 3 + 1) * C; p.bu1 = bl + (l * 3 + 2) * C;
    p.lnwU = lnw + (l * 2 + 0) * C; p.lnbU = lnb + (l * 2 + 0) * C; p.outU = out_u;
    p.Ai0 = mui; p.Ai1 = xib; p.BtI = BtI + (size_t)l * C * 256;
    p.bi0 = bl + (l * 3 + 0) * C;
    p.lnwI = lnw + (l * 2 + 1) * C; p.lnbI = lnb + (l * 2 + 1) * C; p.outI = out_i;
    p.outUb = (l == 0) ? x1ub : nullptr;
    p.outIb = (l == 0) ? x1ib : nullptr;
    p.gbU = gbU;
    gemm_mfma_ln<<<gbU + gbI, 256, 0, stream>>>(p);
  }
}